// Round 1
// baseline (2677.783 us; speedup 1.0000x reference)
//
#include <hip/hip_runtime.h>
#include <math.h>

#define NPTS 576
#define N2 331776           // 576*576
#define BSZ 4
#define NB 64               // cholesky block
#define NT 9                // 576/64

__device__ __constant__ float kL2 = 0.29311396f;      // 0.5414^2
#define INVL2 (1.0f/0.29311396f)

// ---------------------------------------------------------------------------
// small helpers
// ---------------------------------------------------------------------------
__device__ inline float wave_sum(float v) {
    #pragma unroll
    for (int m = 32; m > 0; m >>= 1) v += __shfl_xor(v, m, 64);
    return v;
}

// ---------------------------------------------------------------------------
// copy xout = xin  (output 0)
// ---------------------------------------------------------------------------
__global__ void copy_xout(const float* __restrict__ xin, float* __restrict__ out) {
    int idx = blockIdx.x * 256 + threadIdx.x;   // 18*256 = 4608 exact
    out[idx] = xin[idx];
}

// ---------------------------------------------------------------------------
// build Kxx (+jitter) and opiK (4 planes) from xin
// ---------------------------------------------------------------------------
__global__ void build_k(const float* __restrict__ xin,
                        float* __restrict__ Kxx, float* __restrict__ opiK) {
    int idx = blockIdx.x * 256 + threadIdx.x;   // bs*N2 exact multiple of 256
    int b = idx / N2;
    int rem = idx - b * N2;
    int m = rem / NPTS;
    int nn = rem - m * NPTS;
    const float* xb = xin + (size_t)b * NPTS * 2;
    float xm0 = xb[m*2],  xm1 = xb[m*2+1];
    float xn0 = xb[nn*2], xn1 = xb[nn*2+1];
    float r0 = xm0 - xn0, r1 = xm1 - xn1;
    float u = (r0*r0 + r1*r1) * INVL2;
    float Kv = expf(-0.5f * u);
    Kxx[idx] = Kv + ((m == nn) ? 1e-5f : 0.0f);
    size_t base = (size_t)b * 4 * N2 + rem;
    opiK[base]          = Kv;
    opiK[base + N2]     = -r0 * INVL2 * Kv;
    opiK[base + 2*N2]   = -r1 * INVL2 * Kv;
    opiK[base + 3*N2]   = (u - 2.0f) * INVL2 * Kv;
}

// ---------------------------------------------------------------------------
// W2[i][j] = (1/64) sum_{o,c} w[o][c*4+i] * w[o][c*4+j]
// ---------------------------------------------------------------------------
__global__ void w2_k(const float* __restrict__ w, float* __restrict__ W2) {
    __shared__ float red[256];
    int tid = threadIdx.x;
    int pair = tid & 15;     // i*4+j
    int slice = tid >> 4;    // 0..15 -> o-range
    int i = pair >> 2, j = pair & 3;
    float s = 0.0f;
    for (int o = slice * 4; o < slice * 4 + 4; ++o)
        for (int c = 0; c < 32; ++c)
            s += w[o*128 + c*4 + i] * w[o*128 + c*4 + j];
    red[tid] = s;
    __syncthreads();
    if (tid < 16) {
        float t = 0.0f;
        #pragma unroll
        for (int k = 0; k < 16; ++k) t += red[pair + 16*k];
        W2[pair] = t * (1.0f/64.0f);
    }
}

// ---------------------------------------------------------------------------
// blocked Cholesky: diag factor + Linv_kk of the 64x64 diagonal block
// ---------------------------------------------------------------------------
__global__ void chol_diag(float* __restrict__ A, float* __restrict__ LinvKK, int kb) {
    int b = blockIdx.x;
    float* Ab = A + (size_t)b * N2;
    __shared__ float T[NB][NB+1];
    __shared__ float V[NB][NB+1];
    int tid = threadIdx.x;   // 256
    int r0 = kb * NB;
    for (int idx = tid; idx < NB*NB; idx += 256) {
        int r = idx / NB, c = idx % NB;
        T[r][c] = Ab[(size_t)(r0 + r) * NPTS + r0 + c];
        V[r][c] = 0.0f;
    }
    __syncthreads();
    for (int j = 0; j < NB; ++j) {
        if (tid == 0) T[j][j] = sqrtf(fmaxf(T[j][j], 1e-12f));
        __syncthreads();
        float dj = T[j][j];
        for (int i = j + 1 + tid; i < NB; i += 256) T[i][j] /= dj;
        __syncthreads();
        int tr = NB - 1 - j;
        for (int idx = tid; idx < tr * tr; idx += 256) {
            int i = j + 1 + idx / tr;
            int c = j + 1 + idx % tr;
            T[i][c] -= T[i][j] * T[c][j];
        }
        __syncthreads();
    }
    // Linv_kk by forward substitution, one column per thread (tid<64)
    if (tid < NB) {
        int c = tid;
        for (int i = c; i < NB; ++i) {
            float s = (i == c) ? 1.0f : 0.0f;
            for (int k = c; k < i; ++k) s -= T[i][k] * V[k][c];
            V[i][c] = s / T[i][i];
        }
    }
    __syncthreads();
    float* Vg = LinvKK + ((size_t)b * NT + kb) * NB * NB;
    for (int idx = tid; idx < NB*NB; idx += 256) {
        int r = idx / NB, c = idx % NB;
        if (c <= r) Ab[(size_t)(r0 + r) * NPTS + r0 + c] = T[r][c];
        Vg[idx] = V[r][c];
    }
}

// panel TRSM: L[ib,kb] = A[ib,kb] @ Linv_kk^T
__global__ void chol_trsm(float* __restrict__ A, const float* __restrict__ LinvKK, int kb) {
    int b = blockIdx.y;
    int ib = kb + 1 + blockIdx.x;
    float* Ab = A + (size_t)b * N2;
    const float* Vg = LinvKK + ((size_t)b * NT + kb) * NB * NB;
    __shared__ float At[NB][NB+1];
    __shared__ float Vs[NB][NB+1];
    int tid = threadIdx.x;
    int r0 = ib * NB, c0 = kb * NB;
    for (int idx = tid; idx < NB*NB; idx += 256) {
        int r = idx / NB, c = idx % NB;
        At[r][c] = Ab[(size_t)(r0 + r) * NPTS + c0 + c];
        Vs[r][c] = Vg[idx];
    }
    __syncthreads();
    int tx = tid & 15, ty = tid >> 4;
    float acc[4][4] = {};
    for (int k = 0; k < NB; ++k) {
        float a[4], v[4];
        #pragma unroll
        for (int i = 0; i < 4; ++i) a[i] = At[ty*4+i][k];
        #pragma unroll
        for (int j = 0; j < 4; ++j) v[j] = Vs[tx*4+j][k];
        #pragma unroll
        for (int i = 0; i < 4; ++i)
            #pragma unroll
            for (int j = 0; j < 4; ++j) acc[i][j] += a[i] * v[j];
    }
    __syncthreads();
    #pragma unroll
    for (int i = 0; i < 4; ++i)
        #pragma unroll
        for (int j = 0; j < 4; ++j)
            Ab[(size_t)(r0 + ty*4+i) * NPTS + c0 + tx*4+j] = acc[i][j];
}

// trailing SYRK: A[ib,jb] -= L[ib,kb] @ L[jb,kb]^T  (jb<=ib in trailing)
__global__ void chol_syrk(float* __restrict__ A, int kb) {
    int b = blockIdx.y;
    int p = blockIdx.x;
    int ib_rel = 0;
    while (p >= ib_rel + 1) { p -= ib_rel + 1; ib_rel++; }
    int ib = kb + 1 + ib_rel, jb = kb + 1 + p;
    float* Ab = A + (size_t)b * N2;
    __shared__ float Pi[NB][NB+1];
    __shared__ float Pj[NB][NB+1];
    int tid = threadIdx.x;
    int ri = ib * NB, rj = jb * NB, c0 = kb * NB;
    for (int idx = tid; idx < NB*NB; idx += 256) {
        int r = idx / NB, c = idx % NB;
        Pi[r][c] = Ab[(size_t)(ri + r) * NPTS + c0 + c];
        Pj[r][c] = Ab[(size_t)(rj + r) * NPTS + c0 + c];
    }
    __syncthreads();
    int tx = tid & 15, ty = tid >> 4;
    float acc[4][4] = {};
    for (int k = 0; k < NB; ++k) {
        float a[4], v[4];
        #pragma unroll
        for (int i = 0; i < 4; ++i) a[i] = Pi[ty*4+i][k];
        #pragma unroll
        for (int j = 0; j < 4; ++j) v[j] = Pj[tx*4+j][k];
        #pragma unroll
        for (int i = 0; i < 4; ++i)
            #pragma unroll
            for (int j = 0; j < 4; ++j) acc[i][j] += a[i] * v[j];
    }
    #pragma unroll
    for (int i = 0; i < 4; ++i)
        #pragma unroll
        for (int j = 0; j < 4; ++j)
            Ab[(size_t)(ri + ty*4+i) * NPTS + rj + tx*4+j] -= acc[i][j];
}

// ---------------------------------------------------------------------------
// triangular inverse: Linv column j by forward substitution, one wave/column
// ---------------------------------------------------------------------------
__global__ void trinv_k(const float* __restrict__ L, float* __restrict__ Linv) {
    int b = blockIdx.y;
    int j = blockIdx.x;
    const float* Lb = L + (size_t)b * N2;
    float* Xb = Linv + (size_t)b * N2;
    __shared__ float x[NPTS];
    int lane = threadIdx.x;   // 64
    for (int i = lane; i < NPTS; i += 64) x[i] = 0.0f;
    __syncthreads();
    for (int i = j; i < NPTS; ++i) {
        const float* Lrow = Lb + (size_t)i * NPTS;
        float s = 0.0f;
        for (int k = j + lane; k < i; k += 64) s += Lrow[k] * x[k];
        s = wave_sum(s);
        if (lane == 0) {
            float v = (i == j) ? 1.0f : 0.0f;
            x[i] = (v - s) / Lrow[i];
        }
        __syncthreads();
    }
    for (int i = lane; i < NPTS; i += 64) Xb[(size_t)i * NPTS + j] = x[i];
}

// ---------------------------------------------------------------------------
// generic batched tiled matmul, 128x128 C-tile, 256 threads, 8x8 micro-tile
// TA=1: operand A accessed transposed (C = A^T B).  TB=1: C = A B^T.
// EPI: 0 none, 1 subtract identity, 2 add analytic prior + jitter (final AKA)
// ---------------------------------------------------------------------------
template<int TA, int TB, int EPI>
__global__ __launch_bounds__(256)
void mm_kernel(const float* __restrict__ Aall, const float* __restrict__ Ball,
               float* __restrict__ Call,
               int M, int N, int K, int planeK,
               int lda, int ldb, int ldc,
               long sA, long sB, long sC, long pA, long pB,
               const float* __restrict__ xin, const float* __restrict__ W2)
{
    int b = blockIdx.z;
    const float* A = Aall + (size_t)b * sA;
    const float* B = Ball + (size_t)b * sB;
    float* C = Call + (size_t)b * sC;
    int n0 = blockIdx.x * 128;
    int m0 = blockIdx.y * 128;

    __shared__ float As[16][132];
    __shared__ float Bs[16][132];

    int tid = threadIdx.x;
    int tx = tid & 15, ty = tid >> 4;

    float acc[2][2][4][4] = {};
    bool mFull = (m0 + 128 <= M);
    bool nFull = (n0 + 128 <= N);

    for (int k0 = 0; k0 < K; k0 += 16) {
        int plane = k0 / planeK;
        int koff = k0 - plane * planeK;
        if (TA == 0) {
            const float* Ab = A + (size_t)pA * plane;
            int r = tid >> 2;
            int c4 = (tid & 3) * 4;
            #pragma unroll
            for (int pass = 0; pass < 2; ++pass) {
                int rr = r + pass * 64;
                int gm = m0 + rr;
                float v0=0,v1=0,v2=0,v3=0;
                if (mFull || gm < M) {
                    const float* p = Ab + (size_t)gm * lda + koff + c4;
                    float4 t = *(const float4*)p;
                    v0=t.x; v1=t.y; v2=t.z; v3=t.w;
                }
                As[c4+0][rr]=v0; As[c4+1][rr]=v1; As[c4+2][rr]=v2; As[c4+3][rr]=v3;
            }
        } else {
            int r = tid >> 4;
            int c8 = (tid & 15) * 8;
            const float* p = A + (size_t)(koff + r) * lda + m0 + c8;
            if (mFull) {
                *(float4*)&As[r][c8]   = *(const float4*)p;
                *(float4*)&As[r][c8+4] = *(const float4*)(p + 4);
            } else {
                #pragma unroll
                for (int jj = 0; jj < 8; ++jj)
                    As[r][c8+jj] = (m0 + c8 + jj < M) ? p[jj] : 0.0f;
            }
        }
        if (TB == 0) {
            int r = tid >> 4;
            int c8 = (tid & 15) * 8;
            const float* p = B + (size_t)(koff + r) * ldb + n0 + c8;
            if (nFull) {
                *(float4*)&Bs[r][c8]   = *(const float4*)p;
                *(float4*)&Bs[r][c8+4] = *(const float4*)(p + 4);
            } else {
                #pragma unroll
                for (int jj = 0; jj < 8; ++jj)
                    Bs[r][c8+jj] = (n0 + c8 + jj < N) ? p[jj] : 0.0f;
            }
        } else {
            const float* Bb = B + (size_t)pB * plane;
            int r = tid >> 2;
            int c4 = (tid & 3) * 4;
            #pragma unroll
            for (int pass = 0; pass < 2; ++pass) {
                int rr = r + pass * 64;
                int gp = n0 + rr;
                float v0=0,v1=0,v2=0,v3=0;
                if (nFull || gp < N) {
                    const float* p = Bb + (size_t)gp * ldb + koff + c4;
                    float4 t = *(const float4*)p;
                    v0=t.x; v1=t.y; v2=t.z; v3=t.w;
                }
                Bs[c4+0][rr]=v0; Bs[c4+1][rr]=v1; Bs[c4+2][rr]=v2; Bs[c4+3][rr]=v3;
            }
        }
        __syncthreads();
        #pragma unroll
        for (int kk = 0; kk < 16; ++kk) {
            float a[2][4], bb[2][4];
            *(float4*)a[0]  = *(const float4*)&As[kk][ty*4];
            *(float4*)a[1]  = *(const float4*)&As[kk][64 + ty*4];
            *(float4*)bb[0] = *(const float4*)&Bs[kk][tx*4];
            *(float4*)bb[1] = *(const float4*)&Bs[kk][64 + tx*4];
            #pragma unroll
            for (int ih = 0; ih < 2; ++ih)
                #pragma unroll
                for (int jh = 0; jh < 2; ++jh)
                    #pragma unroll
                    for (int i = 0; i < 4; ++i)
                        #pragma unroll
                        for (int j = 0; j < 4; ++j)
                            acc[ih][jh][i][j] += a[ih][i] * bb[jh][j];
        }
        __syncthreads();
    }

    float w[16];
    float xm[2][4][2], xp[2][4][2];
    if (EPI == 2) {
        #pragma unroll
        for (int q = 0; q < 16; ++q) w[q] = W2[q];
        const float* xb = xin + (size_t)b * NPTS * 2;
        #pragma unroll
        for (int ih = 0; ih < 2; ++ih)
            #pragma unroll
            for (int i = 0; i < 4; ++i) {
                int gm = m0 + ih*64 + ty*4 + i;
                bool ok = gm < M;
                xm[ih][i][0] = ok ? xb[gm*2+0] : 0.0f;
                xm[ih][i][1] = ok ? xb[gm*2+1] : 0.0f;
            }
        #pragma unroll
        for (int jh = 0; jh < 2; ++jh)
            #pragma unroll
            for (int j = 0; j < 4; ++j) {
                int gn = n0 + jh*64 + tx*4 + j;
                bool ok = gn < N;
                xp[jh][j][0] = ok ? xb[gn*2+0] : 0.0f;
                xp[jh][j][1] = ok ? xb[gn*2+1] : 0.0f;
            }
    }

    #pragma unroll
    for (int ih = 0; ih < 2; ++ih)
        #pragma unroll
        for (int i = 0; i < 4; ++i) {
            int gm = m0 + ih*64 + ty*4 + i;
            if (gm >= M) continue;
            #pragma unroll
            for (int jh = 0; jh < 2; ++jh)
                #pragma unroll
                for (int j = 0; j < 4; ++j) {
                    int gn = n0 + jh*64 + tx*4 + j;
                    if (gn >= N) continue;
                    float v = acc[ih][jh][i][j];
                    if (EPI == 1 && gm == gn) v -= 1.0f;
                    if (EPI == 2) {
                        float r0 = xm[ih][i][0] - xp[jh][j][0];
                        float r1 = xm[ih][i][1] - xp[jh][j][1];
                        float u = (r0*r0 + r1*r1) * INVL2;
                        float Kv = expf(-0.5f * u);
                        float i2 = INVL2 * INVL2;
                        float gK0 = r0 * INVL2 * Kv;
                        float gK1 = r1 * INVL2 * Kv;
                        float lapK = (u - 2.0f) * INVL2 * Kv;
                        float gg00 = (INVL2 - r0*r0*i2) * Kv;
                        float gg01 = (-r0*r1*i2) * Kv;
                        float gg11 = (INVL2 - r1*r1*i2) * Kv;
                        float gl0 = r0 * i2 * (4.0f - u) * Kv;
                        float gl1 = r1 * i2 * (4.0f - u) * Kv;
                        float ll = ((u-2.0f)*(u-2.0f) - 4.0f*u + 4.0f) * i2 * Kv;
                        float prior =
                              w[0]*Kv + w[1]*gK0 + w[2]*gK1 + w[3]*lapK
                            + w[4]*(-gK0) + w[5]*gg00 + w[6]*gg01 + w[7]*gl0
                            + w[8]*(-gK1) + w[9]*gg01 + w[10]*gg11 + w[11]*gl1
                            + w[12]*lapK + w[13]*(-gl0) + w[14]*(-gl1) + w[15]*ll;
                        v += prior;
                        if (gm == gn) v += 1.1e-4f;   // JITTER_AKA + JITTER_YY
                    }
                    C[(size_t)gm * ldc + gn] = v;
                }
        }
}

// ---------------------------------------------------------------------------
// opiKW2[b][i] = sum_j W2[i][j] * opiK[b][j]   (elementwise over (m,n))
// ---------------------------------------------------------------------------
__global__ void opiw2_k(const float* __restrict__ opiK, const float* __restrict__ W2,
                        float* __restrict__ outB) {
    int idx = blockIdx.x * 256 + threadIdx.x;
    int b = idx / N2;
    int rem = idx - b * N2;
    size_t base = (size_t)b * 4 * N2 + rem;
    float k0 = opiK[base], k1 = opiK[base + N2], k2 = opiK[base + 2*N2], k3 = opiK[base + 3*N2];
    #pragma unroll
    for (int i = 0; i < 4; ++i)
        outB[base + (size_t)i * N2] = W2[i*4+0]*k0 + W2[i*4+1]*k1 + W2[i*4+2]*k2 + W2[i*4+3]*k3;
}

// ---------------------------------------------------------------------------
// Amean[b,m,o] = sum_{c,k} opimean[b,k,m,c] * weight[o, c*4+k] + bias[o]
// ---------------------------------------------------------------------------
__global__ __launch_bounds__(256)
void amean_k(const float* __restrict__ opimean, const float* __restrict__ weight,
             const float* __restrict__ bias, float* __restrict__ out) {
    int b = blockIdx.y;
    int m0 = blockIdx.x * 32;
    __shared__ float Wl[64][128];
    __shared__ float om[32][128];
    int tid = threadIdx.x;
    for (int idx = tid; idx < 64*128; idx += 256) Wl[idx / 128][idx & 127] = weight[idx];
    for (int idx = tid; idx < 32*128; idx += 256) {
        int m = idx >> 7, ck = idx & 127, c = ck >> 2, kop = ck & 3;
        om[m][ck] = opimean[((size_t)b * 4 + kop) * NPTS * 32 + (size_t)(m0 + m) * 32 + c];
    }
    __syncthreads();
    int ml = tid >> 3, o0 = (tid & 7) * 8;
    float acc[8] = {};
    for (int ck = 0; ck < 128; ++ck) {
        float v = om[ml][ck];
        #pragma unroll
        for (int q = 0; q < 8; ++q) acc[q] += v * Wl[o0+q][ck];
    }
    #pragma unroll
    for (int q = 0; q < 8; ++q)
        out[4608 + ((size_t)b * NPTS + m0 + ml) * 64 + o0 + q] = acc[q] + bias[o0+q];
}

// ---------------------------------------------------------------------------
extern "C" void kernel_launch(void* const* d_in, const int* in_sizes, int n_in,
                              void* d_out, int out_size, void* d_ws, size_t ws_size,
                              hipStream_t stream) {
    const float* xin    = (const float*)d_in[0];
    const float* meanin = (const float*)d_in[1];
    const float* Kin    = (const float*)d_in[2];
    const float* weight = (const float*)d_in[3];
    const float* bias   = (const float*)d_in[4];
    float* out = (float*)d_out;
    float* ws  = (float*)d_ws;

    const long N2L = N2;
    float* W2      = ws;                       // 16 (pad 64)
    float* LinvKK  = ws + 64;                  // 4*9*4096 = 147456
    float* bufL    = LinvKK + 147456;          // 4*N2  (L, later interpW - I)
    float* bufLinv = bufL + 4*N2L;             // 4*N2  (Linv, later sol_mean/opimean)
    float* bufKinv = bufLinv + 4*N2L;          // 4*N2
    float* opiK    = bufKinv + 4*N2L;          // 16*N2
    float* bufB    = opiK + 16*N2L;            // 16*N2 (KiO, later opiKW2)
    float* bufC    = bufB + 16*N2L;            // 16*N2 (H')
    float* solm    = bufLinv;                  // reuse after Kinv done
    float* opim    = bufLinv + 73728;

    // output 0: xout = xin
    copy_xout<<<dim3(18), dim3(256), 0, stream>>>(xin, out);
    // Kxx (+jitter) and opiK
    build_k<<<dim3((BSZ*N2)/256), dim3(256), 0, stream>>>(xin, bufL, opiK);
    // W2
    w2_k<<<dim3(1), dim3(256), 0, stream>>>(weight, W2);
    // blocked Cholesky of Kxx -> L (lower) in bufL
    for (int kb = 0; kb < NT; ++kb) {
        chol_diag<<<dim3(BSZ), dim3(256), 0, stream>>>(bufL, LinvKK, kb);
        int t = NT - 1 - kb;
        if (t > 0) {
            chol_trsm<<<dim3(t, BSZ), dim3(256), 0, stream>>>(bufL, LinvKK, kb);
            chol_syrk<<<dim3(t*(t+1)/2, BSZ), dim3(256), 0, stream>>>(bufL, kb);
        }
    }
    // Linv (full lower-triangular inverse)
    trinv_k<<<dim3(NPTS, BSZ), dim3(64), 0, stream>>>(bufL, bufLinv);
    // Kinv = Linv^T @ Linv
    mm_kernel<1,0,0><<<dim3(5,5,BSZ), dim3(256), 0, stream>>>(
        bufLinv, bufLinv, bufKinv, 576,576,576,576, 576,576,576,
        N2L,N2L,N2L, 0,0, nullptr, nullptr);
    // sol_mean = Kinv @ meanin
    mm_kernel<0,0,0><<<dim3(1,5,BSZ), dim3(256), 0, stream>>>(
        bufKinv, meanin, solm, 576,32,576,576, 576,32,32,
        N2L,18432,18432, 0,0, nullptr, nullptr);
    // opimean = opiK @ sol_mean
    mm_kernel<0,0,0><<<dim3(1,18,BSZ), dim3(256), 0, stream>>>(
        opiK, solm, opim, 2304,32,576,576, 576,32,32,
        4*N2L,18432,73728, 0,0, nullptr, nullptr);
    // Amean (output 1)
    amean_k<<<dim3(18,BSZ), dim3(256), 0, stream>>>(opim, weight, bias, out);
    // interpW - I = Kin @ Kinv - I  (into bufL, L no longer needed)
    mm_kernel<0,0,1><<<dim3(5,5,BSZ), dim3(256), 0, stream>>>(
        Kin, bufKinv, bufL, 576,576,576,576, 576,576,576,
        N2L,N2L,N2L, 0,0, nullptr, nullptr);
    // KiO = opiK @ Kinv
    mm_kernel<0,0,0><<<dim3(5,18,BSZ), dim3(256), 0, stream>>>(
        opiK, bufKinv, bufB, 2304,576,576,576, 576,576,576,
        4*N2L,N2L,4*N2L, 0,0, nullptr, nullptr);
    // H' = KiO @ (interpW - I)
    mm_kernel<0,0,0><<<dim3(5,18,BSZ), dim3(256), 0, stream>>>(
        bufB, bufL, bufC, 2304,576,576,576, 576,576,576,
        4*N2L,N2L,4*N2L, 0,0, nullptr, nullptr);
    // opiKW2 = W2 x opiK  (into bufB, KiO consumed)
    opiw2_k<<<dim3((BSZ*N2)/256), dim3(256), 0, stream>>>(opiK, W2, bufB);
    // full_AKA (output 2): prior + sum_{i,n} H'[i,m,n]*opiKW2[i,p,n] + jitter
    mm_kernel<0,1,2><<<dim3(5,5,BSZ), dim3(256), 0, stream>>>(
        bufC, bufB, out + 152064, 576,576,2304,576, 576,576,576,
        4*N2L,4*N2L,N2L, N2L,N2L, xin, W2);
}

// Round 3
// 1746.292 us; speedup vs baseline: 1.5334x; 1.5334x over previous
//
#include <hip/hip_runtime.h>
#include <math.h>

#define NPTS 576
#define N2 331776           // 576*576
#define BSZ 4
#define NB 64               // cholesky block
#define NT 9                // 576/64

#define INVL2 (1.0f/0.29311396f)

// ---------------------------------------------------------------------------
// copy xout = xin  (output 0)
// ---------------------------------------------------------------------------
__global__ void copy_xout(const float* __restrict__ xin, float* __restrict__ out) {
    int idx = blockIdx.x * 256 + threadIdx.x;   // 18*256 = 4608 exact
    out[idx] = xin[idx];
}

// ---------------------------------------------------------------------------
// build Kxx (+jitter) and opiK (4 planes) from xin
// ---------------------------------------------------------------------------
__global__ void build_k(const float* __restrict__ xin,
                        float* __restrict__ Kxx, float* __restrict__ opiK) {
    int idx = blockIdx.x * 256 + threadIdx.x;
    int b = idx / N2;
    int rem = idx - b * N2;
    int m = rem / NPTS;
    int nn = rem - m * NPTS;
    const float* xb = xin + (size_t)b * NPTS * 2;
    float xm0 = xb[m*2],  xm1 = xb[m*2+1];
    float xn0 = xb[nn*2], xn1 = xb[nn*2+1];
    float r0 = xm0 - xn0, r1 = xm1 - xn1;
    float u = (r0*r0 + r1*r1) * INVL2;
    float Kv = expf(-0.5f * u);
    Kxx[idx] = Kv + ((m == nn) ? 1e-5f : 0.0f);
    size_t base = (size_t)b * 4 * N2 + rem;
    opiK[base]          = Kv;
    opiK[base + N2]     = -r0 * INVL2 * Kv;
    opiK[base + 2*N2]   = -r1 * INVL2 * Kv;
    opiK[base + 3*N2]   = (u - 2.0f) * INVL2 * Kv;
}

// ---------------------------------------------------------------------------
// W2[i][j] = (1/64) sum_{o,c} w[o][c*4+i] * w[o][c*4+j]
// ---------------------------------------------------------------------------
__global__ void w2_k(const float* __restrict__ w, float* __restrict__ W2) {
    __shared__ float red[256];
    int tid = threadIdx.x;
    int pair = tid & 15;
    int slice = tid >> 4;
    int i = pair >> 2, j = pair & 3;
    float s = 0.0f;
    for (int o = slice * 4; o < slice * 4 + 4; ++o)
        for (int c = 0; c < 32; ++c)
            s += w[o*128 + c*4 + i] * w[o*128 + c*4 + j];
    red[tid] = s;
    __syncthreads();
    if (tid < 16) {
        float t = 0.0f;
        #pragma unroll
        for (int k = 0; k < 16; ++k) t += red[pair + 16*k];
        W2[pair] = t * (1.0f/64.0f);
    }
}

// ---------------------------------------------------------------------------
// blocked Cholesky: diag factor + Linv_kk (64x64) via 16x16 sub-block scheme
// ---------------------------------------------------------------------------
__global__ void chol_diag(float* __restrict__ A, float* __restrict__ LinvKK, int kb) {
    int b = blockIdx.x;
    float* Ab = A + (size_t)b * N2;
    __shared__ float T[NB][NB+1];
    __shared__ float V[NB][NB+1];
    __shared__ float tmp[16][17];
    int tid = threadIdx.x;   // 256
    int r0 = kb * NB;
    for (int idx = tid; idx < NB*NB; idx += 256) {
        int r = idx >> 6, c = idx & 63;
        T[r][c] = Ab[(size_t)(r0 + r) * NPTS + r0 + c];
        V[r][c] = 0.0f;
    }
    __syncthreads();
    // factor
    for (int j = 0; j < NB; ++j) {
        if (tid == 0) T[j][j] = sqrtf(fmaxf(T[j][j], 1e-12f));
        __syncthreads();
        float dj = T[j][j];
        for (int i = j + 1 + tid; i < NB; i += 256) T[i][j] /= dj;
        __syncthreads();
        int tr = NB - 1 - j;
        for (int idx = tid; idx < tr * tr; idx += 256) {
            int i = j + 1 + idx / tr;
            int c = j + 1 + idx % tr;
            T[i][c] -= T[i][j] * T[c][j];
        }
        __syncthreads();
    }
    // invert the four 16x16 diagonal sub-blocks (64 parallel column-solves)
    if (tid < 64) {
        int I = tid >> 4, c = tid & 15, base = I * 16;
        for (int i = c; i < 16; ++i) {
            float s = (i == c) ? 1.0f : 0.0f;
            for (int k = c; k < i; ++k) s -= T[base+i][base+k] * V[base+k][base+c];
            V[base+i][base+c] = s / T[base+i][base+i];
        }
    }
    __syncthreads();
    // off-diagonal sub-blocks by level: V[I][J] = -Vd[I] * (sum_K T[I][K] V[K][J])
    const int PI[6] = {1,2,3,2,3,3};
    const int PJ[6] = {0,1,2,0,1,0};
    int rr16 = tid >> 4, cc16 = tid & 15;
    for (int p = 0; p < 6; ++p) {
        int I = PI[p], J = PJ[p];
        float s = 0.0f;
        for (int K = J; K < I; ++K)
            #pragma unroll
            for (int t = 0; t < 16; ++t)
                s += T[I*16+rr16][K*16+t] * V[K*16+t][J*16+cc16];
        tmp[rr16][cc16] = s;
        __syncthreads();
        float s2 = 0.0f;
        for (int t = 0; t <= rr16; ++t) s2 += V[I*16+rr16][I*16+t] * tmp[t][cc16];
        __syncthreads();
        V[I*16+rr16][J*16+cc16] = -s2;
        __syncthreads();
    }
    // write back T (lower) and V
    float* Vg = LinvKK + ((size_t)b * NT + kb) * NB * NB;
    for (int idx = tid; idx < NB*NB; idx += 256) {
        int r = idx >> 6, c = idx & 63;
        if (c <= r) Ab[(size_t)(r0 + r) * NPTS + r0 + c] = T[r][c];
        Vg[idx] = V[r][c];
    }
}

// panel TRSM: L[ib,kb] = A[ib,kb] @ Linv_kk^T
__global__ void chol_trsm(float* __restrict__ A, const float* __restrict__ LinvKK, int kb) {
    int b = blockIdx.y;
    int ib = kb + 1 + blockIdx.x;
    float* Ab = A + (size_t)b * N2;
    const float* Vg = LinvKK + ((size_t)b * NT + kb) * NB * NB;
    __shared__ float At[NB][NB+1];
    __shared__ float Vs[NB][NB+1];
    int tid = threadIdx.x;
    int r0 = ib * NB, c0 = kb * NB;
    for (int idx = tid; idx < NB*NB; idx += 256) {
        int r = idx >> 6, c = idx & 63;
        At[r][c] = Ab[(size_t)(r0 + r) * NPTS + c0 + c];
        Vs[r][c] = Vg[idx];
    }
    __syncthreads();
    int tx = tid & 15, ty = tid >> 4;
    float acc[4][4] = {};
    for (int k = 0; k < NB; ++k) {
        float a[4], v[4];
        #pragma unroll
        for (int i = 0; i < 4; ++i) a[i] = At[ty*4+i][k];
        #pragma unroll
        for (int j = 0; j < 4; ++j) v[j] = Vs[tx*4+j][k];
        #pragma unroll
        for (int i = 0; i < 4; ++i)
            #pragma unroll
            for (int j = 0; j < 4; ++j) acc[i][j] += a[i] * v[j];
    }
    __syncthreads();
    #pragma unroll
    for (int i = 0; i < 4; ++i)
        #pragma unroll
        for (int j = 0; j < 4; ++j)
            Ab[(size_t)(r0 + ty*4+i) * NPTS + c0 + tx*4+j] = acc[i][j];
}

// trailing SYRK: A[ib,jb] -= L[ib,kb] @ L[jb,kb]^T
__global__ void chol_syrk(float* __restrict__ A, int kb) {
    int b = blockIdx.y;
    int p = blockIdx.x;
    int ib_rel = 0;
    while (p >= ib_rel + 1) { p -= ib_rel + 1; ib_rel++; }
    int ib = kb + 1 + ib_rel, jb = kb + 1 + p;
    float* Ab = A + (size_t)b * N2;
    __shared__ float Pi[NB][NB+1];
    __shared__ float Pj[NB][NB+1];
    int tid = threadIdx.x;
    int ri = ib * NB, rj = jb * NB, c0 = kb * NB;
    for (int idx = tid; idx < NB*NB; idx += 256) {
        int r = idx >> 6, c = idx & 63;
        Pi[r][c] = Ab[(size_t)(ri + r) * NPTS + c0 + c];
        Pj[r][c] = Ab[(size_t)(rj + r) * NPTS + c0 + c];
    }
    __syncthreads();
    int tx = tid & 15, ty = tid >> 4;
    float acc[4][4] = {};
    for (int k = 0; k < NB; ++k) {
        float a[4], v[4];
        #pragma unroll
        for (int i = 0; i < 4; ++i) a[i] = Pi[ty*4+i][k];
        #pragma unroll
        for (int j = 0; j < 4; ++j) v[j] = Pj[tx*4+j][k];
        #pragma unroll
        for (int i = 0; i < 4; ++i)
            #pragma unroll
            for (int j = 0; j < 4; ++j) acc[i][j] += a[i] * v[j];
    }
    #pragma unroll
    for (int i = 0; i < 4; ++i)
        #pragma unroll
        for (int j = 0; j < 4; ++j)
            Ab[(size_t)(ri + ty*4+i) * NPTS + rj + tx*4+j] -= acc[i][j];
}

// ---------------------------------------------------------------------------
// blocked triangular inverse. grid (4 splits of 16 cols, 9 block-cols, 4 batch)
// X[i][jb] = -Linv_ii * sum_{k=jb..i-1} L[i][k] X[k][jb],  X[jb][jb]=Linv_jbjb
// ---------------------------------------------------------------------------
__global__ __launch_bounds__(256)
void trinv_blk(const float* __restrict__ L, const float* __restrict__ LinvKK,
               float* __restrict__ Linv) {
    int sp = blockIdx.x, jb = blockIdx.y, b = blockIdx.z;
    const float* Lb = L + (size_t)b * N2;
    float* Xg = Linv + (size_t)b * N2;
    const float* Vg = LinvKK + (size_t)b * NT * NB * NB;
    int c0 = jb * NB + sp * 16;

    __shared__ float LsT[64][72];     // transposed operand tile
    __shared__ float Xc[576][17];     // X blocks (relative row index), 16 cols
    __shared__ float Ss[64][17];      // S staging for TRMM

    int tid = threadIdx.x;
    int tx = tid & 15, ty = tid >> 4;

    // step 0: X[jb] = Linv_jbjb (cols sp*16..+16)
    {
        const float* Vjj = Vg + (size_t)jb * NB * NB;
        int r = tid >> 2, c4 = (tid & 3) * 4;
        float4 v = *(const float4*)(Vjj + r * NB + sp * 16 + c4);
        Xc[r][c4+0] = v.x; Xc[r][c4+1] = v.y; Xc[r][c4+2] = v.z; Xc[r][c4+3] = v.w;
        *(float4*)(Xg + (size_t)(jb * NB + r) * NPTS + c0 + c4) = v;
    }
    __syncthreads();

    for (int ib = jb + 1; ib < NT; ++ib) {
        float acc[4] = {};
        for (int kb = jb; kb < ib; ++kb) {
            {
                int r = tid >> 2, t0 = (tid & 3) * 16;
                const float* src = Lb + (size_t)(ib * NB + r) * NPTS + kb * NB + t0;
                #pragma unroll
                for (int q = 0; q < 4; ++q) {
                    float4 v = *(const float4*)(src + q * 4);
                    LsT[t0 + q*4 + 0][r] = v.x;
                    LsT[t0 + q*4 + 1][r] = v.y;
                    LsT[t0 + q*4 + 2][r] = v.z;
                    LsT[t0 + q*4 + 3][r] = v.w;
                }
            }
            __syncthreads();
            int xbase = (kb - jb) * 64;
            #pragma unroll 8
            for (int t = 0; t < 64; ++t) {
                float a4[4]; *(float4*)a4 = *(const float4*)&LsT[t][ty*4];
                float xv = Xc[xbase + t][tx];
                #pragma unroll
                for (int i = 0; i < 4; ++i) acc[i] += a4[i] * xv;
            }
            __syncthreads();
        }
        #pragma unroll
        for (int i = 0; i < 4; ++i) Ss[ty*4+i][tx] = acc[i];
        {
            const float* Vii = Vg + (size_t)ib * NB * NB;
            int r = tid >> 2, t0 = (tid & 3) * 16;
            #pragma unroll
            for (int q = 0; q < 4; ++q) {
                float4 v = *(const float4*)(Vii + r * NB + t0 + q * 4);
                LsT[t0 + q*4 + 0][r] = v.x;
                LsT[t0 + q*4 + 1][r] = v.y;
                LsT[t0 + q*4 + 2][r] = v.z;
                LsT[t0 + q*4 + 3][r] = v.w;
            }
        }
        __syncthreads();
        float acc2[4] = {};
        #pragma unroll 8
        for (int t = 0; t < 64; ++t) {
            float a4[4]; *(float4*)a4 = *(const float4*)&LsT[t][ty*4];
            float sv = Ss[t][tx];
            #pragma unroll
            for (int i = 0; i < 4; ++i) acc2[i] += a4[i] * sv;
        }
        int obase = (ib - jb) * 64;
        #pragma unroll
        for (int i = 0; i < 4; ++i) {
            float v = -acc2[i];
            Xc[obase + ty*4 + i][tx] = v;
            Xg[(size_t)(ib * NB + ty*4 + i) * NPTS + c0 + tx] = v;
        }
        __syncthreads();
    }
}

// ---------------------------------------------------------------------------
// batched tiled matmul, (IH*64)x128 C-tile, 256 threads
// TA=1: C = A^T B.  TB=1: C = A B^T.
// EPI: 0 none, 1 subtract identity, 2 add analytic prior + jitter (final AKA)
// ---------------------------------------------------------------------------
template<int IH, int TA, int TB, int EPI>
__global__ __launch_bounds__(256)
void mm_kernel(const float* __restrict__ Aall, const float* __restrict__ Ball,
               float* __restrict__ Call,
               int M, int N, int K, int planeK,
               int lda, int ldb, int ldc,
               long sA, long sB, long sC, long pA, long pB,
               const float* __restrict__ xin, const float* __restrict__ W2)
{
    int b = blockIdx.z;
    const float* A = Aall + (size_t)b * sA;
    const float* B = Ball + (size_t)b * sB;
    float* C = Call + (size_t)b * sC;
    int n0 = blockIdx.x * 128;
    int m0 = blockIdx.y * (IH * 64);

    __shared__ float As[16][IH*64 + 4];
    __shared__ float Bs[16][132];

    int tid = threadIdx.x;
    int tx = tid & 15, ty = tid >> 4;

    float acc[IH][2][4][4] = {};
    bool mFull = (m0 + IH*64 <= M);
    bool nFull = (n0 + 128 <= N);

    for (int k0 = 0; k0 < K; k0 += 16) {
        int plane = k0 / planeK;
        int koff = k0 - plane * planeK;
        if (TA == 0) {
            const float* Ab = A + (size_t)pA * plane;
            int r = tid >> 2;
            int c4 = (tid & 3) * 4;
            #pragma unroll
            for (int pass = 0; pass < IH; ++pass) {
                int rr = r + pass * 64;
                int gm = m0 + rr;
                float v0=0,v1=0,v2=0,v3=0;
                if (mFull || gm < M) {
                    const float* p = Ab + (size_t)gm * lda + koff + c4;
                    float4 t = *(const float4*)p;
                    v0=t.x; v1=t.y; v2=t.z; v3=t.w;
                }
                As[c4+0][rr]=v0; As[c4+1][rr]=v1; As[c4+2][rr]=v2; As[c4+3][rr]=v3;
            }
        } else {
            if (IH == 2) {
                int r = tid >> 4;
                int c8 = (tid & 15) * 8;
                const float* p = A + (size_t)(koff + r) * lda + m0 + c8;
                if (mFull) {
                    *(float4*)&As[r][c8]   = *(const float4*)p;
                    *(float4*)&As[r][c8+4] = *(const float4*)(p + 4);
                } else {
                    #pragma unroll
                    for (int jj = 0; jj < 8; ++jj)
                        As[r][c8+jj] = (m0 + c8 + jj < M) ? p[jj] : 0.0f;
                }
            } else {
                int r = tid >> 4;
                int c4 = (tid & 15) * 4;
                const float* p = A + (size_t)(koff + r) * lda + m0 + c4;
                if (mFull) {
                    *(float4*)&As[r][c4] = *(const float4*)p;
                } else {
                    #pragma unroll
                    for (int jj = 0; jj < 4; ++jj)
                        As[r][c4+jj] = (m0 + c4 + jj < M) ? p[jj] : 0.0f;
                }
            }
        }
        if (TB == 0) {
            int r = tid >> 4;
            int c8 = (tid & 15) * 8;
            const float* p = B + (size_t)(koff + r) * ldb + n0 + c8;
            if (nFull) {
                *(float4*)&Bs[r][c8]   = *(const float4*)p;
                *(float4*)&Bs[r][c8+4] = *(const float4*)(p + 4);
            } else {
                #pragma unroll
                for (int jj = 0; jj < 8; ++jj)
                    Bs[r][c8+jj] = (n0 + c8 + jj < N) ? p[jj] : 0.0f;
            }
        } else {
            const float* Bb = B + (size_t)pB * plane;
            int r = tid >> 2;
            int c4 = (tid & 3) * 4;
            #pragma unroll
            for (int pass = 0; pass < 2; ++pass) {
                int rr = r + pass * 64;
                int gp = n0 + rr;
                float v0=0,v1=0,v2=0,v3=0;
                if (nFull || gp < N) {
                    const float* p = Bb + (size_t)gp * ldb + koff + c4;
                    float4 t = *(const float4*)p;
                    v0=t.x; v1=t.y; v2=t.z; v3=t.w;
                }
                Bs[c4+0][rr]=v0; Bs[c4+1][rr]=v1; Bs[c4+2][rr]=v2; Bs[c4+3][rr]=v3;
            }
        }
        __syncthreads();
        #pragma unroll
        for (int kk = 0; kk < 16; ++kk) {
            float a[IH][4], bb[2][4];
            #pragma unroll
            for (int ih = 0; ih < IH; ++ih)
                *(float4*)a[ih] = *(const float4*)&As[kk][ih*64 + ty*4];
            *(float4*)bb[0] = *(const float4*)&Bs[kk][tx*4];
            *(float4*)bb[1] = *(const float4*)&Bs[kk][64 + tx*4];
            #pragma unroll
            for (int ih = 0; ih < IH; ++ih)
                #pragma unroll
                for (int jh = 0; jh < 2; ++jh)
                    #pragma unroll
                    for (int i = 0; i < 4; ++i)
                        #pragma unroll
                        for (int j = 0; j < 4; ++j)
                            acc[ih][jh][i][j] += a[ih][i] * bb[jh][j];
        }
        __syncthreads();
    }

    float w[16];
    float xm[IH][4][2], xp[2][4][2];
    if (EPI == 2) {
        #pragma unroll
        for (int q = 0; q < 16; ++q) w[q] = W2[q];
        const float* xb = xin + (size_t)b * NPTS * 2;
        #pragma unroll
        for (int ih = 0; ih < IH; ++ih)
            #pragma unroll
            for (int i = 0; i < 4; ++i) {
                int gm = m0 + ih*64 + ty*4 + i;
                bool ok = gm < M;
                xm[ih][i][0] = ok ? xb[gm*2+0] : 0.0f;
                xm[ih][i][1] = ok ? xb[gm*2+1] : 0.0f;
            }
        #pragma unroll
        for (int jh = 0; jh < 2; ++jh)
            #pragma unroll
            for (int j = 0; j < 4; ++j) {
                int gn = n0 + jh*64 + tx*4 + j;
                bool ok = gn < N;
                xp[jh][j][0] = ok ? xb[gn*2+0] : 0.0f;
                xp[jh][j][1] = ok ? xb[gn*2+1] : 0.0f;
            }
    }

    #pragma unroll
    for (int ih = 0; ih < IH; ++ih)
        #pragma unroll
        for (int i = 0; i < 4; ++i) {
            int gm = m0 + ih*64 + ty*4 + i;
            if (gm >= M) continue;
            #pragma unroll
            for (int jh = 0; jh < 2; ++jh)
                #pragma unroll
                for (int j = 0; j < 4; ++j) {
                    int gn = n0 + jh*64 + tx*4 + j;
                    if (gn >= N) continue;
                    float v = acc[ih][jh][i][j];
                    if (EPI == 1 && gm == gn) v -= 1.0f;
                    if (EPI == 2) {
                        float r0 = xm[ih][i][0] - xp[jh][j][0];
                        float r1 = xm[ih][i][1] - xp[jh][j][1];
                        float u = (r0*r0 + r1*r1) * INVL2;
                        float Kv = expf(-0.5f * u);
                        float i2 = INVL2 * INVL2;
                        float gK0 = r0 * INVL2 * Kv;
                        float gK1 = r1 * INVL2 * Kv;
                        float lapK = (u - 2.0f) * INVL2 * Kv;
                        float gg00 = (INVL2 - r0*r0*i2) * Kv;
                        float gg01 = (-r0*r1*i2) * Kv;
                        float gg11 = (INVL2 - r1*r1*i2) * Kv;
                        float gl0 = r0 * i2 * (4.0f - u) * Kv;
                        float gl1 = r1 * i2 * (4.0f - u) * Kv;
                        float ll = ((u-2.0f)*(u-2.0f) - 4.0f*u + 4.0f) * i2 * Kv;
                        float prior =
                              w[0]*Kv + w[1]*gK0 + w[2]*gK1 + w[3]*lapK
                            + w[4]*(-gK0) + w[5]*gg00 + w[6]*gg01 + w[7]*gl0
                            + w[8]*(-gK1) + w[9]*gg01 + w[10]*gg11 + w[11]*gl1
                            + w[12]*lapK + w[13]*(-gl0) + w[14]*(-gl1) + w[15]*ll;
                        v += prior;
                        if (gm == gn) v += 1.1e-4f;
                    }
                    C[(size_t)gm * ldc + gn] = v;
                }
        }
}

// ---------------------------------------------------------------------------
// opiKW2[b][i] = sum_j W2[i][j] * opiK[b][j]
// ---------------------------------------------------------------------------
__global__ void opiw2_k(const float* __restrict__ opiK, const float* __restrict__ W2,
                        float* __restrict__ outB) {
    int idx = blockIdx.x * 256 + threadIdx.x;
    int b = idx / N2;
    int rem = idx - b * N2;
    size_t base = (size_t)b * 4 * N2 + rem;
    float k0 = opiK[base], k1 = opiK[base + N2], k2 = opiK[base + 2*N2], k3 = opiK[base + 3*N2];
    #pragma unroll
    for (int i = 0; i < 4; ++i)
        outB[base + (size_t)i * N2] = W2[i*4+0]*k0 + W2[i*4+1]*k1 + W2[i*4+2]*k2 + W2[i*4+3]*k3;
}

// ---------------------------------------------------------------------------
// Amean[b,m,o] = sum_{c,k} opimean[b,k,m,c] * weight[o, c*4+k] + bias[o]
// ---------------------------------------------------------------------------
__global__ __launch_bounds__(256)
void amean_k(const float* __restrict__ opimean, const float* __restrict__ weight,
             const float* __restrict__ bias, float* __restrict__ out) {
    int b = blockIdx.y;
    int m0 = blockIdx.x * 32;
    __shared__ float Wl[64][128];
    __shared__ float om[32][128];
    int tid = threadIdx.x;
    for (int idx = tid; idx < 64*128; idx += 256) Wl[idx / 128][idx & 127] = weight[idx];
    for (int idx = tid; idx < 32*128; idx += 256) {
        int m = idx >> 7, ck = idx & 127, c = ck >> 2, kop = ck & 3;
        om[m][ck] = opimean[((size_t)b * 4 + kop) * NPTS * 32 + (size_t)(m0 + m) * 32 + c];
    }
    __syncthreads();
    int ml = tid >> 3, o0 = (tid & 7) * 8;
    float acc[8] = {};
    for (int ck = 0; ck < 128; ++ck) {
        float v = om[ml][ck];
        #pragma unroll
        for (int q = 0; q < 8; ++q) acc[q] += v * Wl[o0+q][ck];
    }
    #pragma unroll
    for (int q = 0; q < 8; ++q)
        out[4608 + ((size_t)b * NPTS + m0 + ml) * 64 + o0 + q] = acc[q] + bias[o0+q];
}

// ---------------------------------------------------------------------------
extern "C" void kernel_launch(void* const* d_in, const int* in_sizes, int n_in,
                              void* d_out, int out_size, void* d_ws, size_t ws_size,
                              hipStream_t stream) {
    const float* xin    = (const float*)d_in[0];
    const float* meanin = (const float*)d_in[1];
    const float* Kin    = (const float*)d_in[2];
    const float* weight = (const float*)d_in[3];
    const float* bias   = (const float*)d_in[4];
    float* out = (float*)d_out;
    float* ws  = (float*)d_ws;

    const long N2L = N2;
    float* W2      = ws;                       // 16 (pad 64)
    float* LinvKK  = ws + 64;                  // 4*9*4096 = 147456
    float* bufL    = LinvKK + 147456;          // 4*N2  (L, later interpW - I)
    float* bufLinv = bufL + 4*N2L;             // 4*N2  (Linv, later solm/opim)
    float* bufKinv = bufLinv + 4*N2L;          // 4*N2
    float* opiK    = bufKinv + 4*N2L;          // 16*N2
    float* bufB    = opiK + 16*N2L;            // 16*N2 (KiO, later opiKW2)
    float* bufC    = bufB + 16*N2L;            // 16*N2 (H')
    float* solm    = bufLinv;                  // reuse after Kinv done
    float* opim    = bufLinv + 73728;

    // zero Linv (upper triangle must be 0)
    hipMemsetAsync(bufLinv, 0, (size_t)4 * N2 * sizeof(float), stream);
    // output 0: xout = xin
    copy_xout<<<dim3(18), dim3(256), 0, stream>>>(xin, out);
    // Kxx (+jitter) and opiK
    build_k<<<dim3((BSZ*N2)/256), dim3(256), 0, stream>>>(xin, bufL, opiK);
    // W2
    w2_k<<<dim3(1), dim3(256), 0, stream>>>(weight, W2);
    // blocked Cholesky of Kxx -> L (lower) in bufL
    for (int kb = 0; kb < NT; ++kb) {
        chol_diag<<<dim3(BSZ), dim3(256), 0, stream>>>(bufL, LinvKK, kb);
        int t = NT - 1 - kb;
        if (t > 0) {
            chol_trsm<<<dim3(t, BSZ), dim3(256), 0, stream>>>(bufL, LinvKK, kb);
            chol_syrk<<<dim3(t*(t+1)/2, BSZ), dim3(256), 0, stream>>>(bufL, kb);
        }
    }
    // blocked triangular inverse -> Linv
    trinv_blk<<<dim3(4, NT, BSZ), dim3(256), 0, stream>>>(bufL, LinvKK, bufLinv);
    // Kinv = Linv^T @ Linv
    mm_kernel<1,1,0,0><<<dim3(5,9,BSZ), dim3(256), 0, stream>>>(
        bufLinv, bufLinv, bufKinv, 576,576,576,576, 576,576,576,
        N2L,N2L,N2L, 0,0, nullptr, nullptr);
    // sol_mean = Kinv @ meanin
    mm_kernel<1,0,0,0><<<dim3(1,9,BSZ), dim3(256), 0, stream>>>(
        bufKinv, meanin, solm, 576,32,576,576, 576,32,32,
        N2L,18432,18432, 0,0, nullptr, nullptr);
    // opimean = opiK @ sol_mean
    mm_kernel<2,0,0,0><<<dim3(1,18,BSZ), dim3(256), 0, stream>>>(
        opiK, solm, opim, 2304,32,576,576, 576,32,32,
        4*N2L,18432,73728, 0,0, nullptr, nullptr);
    // Amean (output 1)
    amean_k<<<dim3(18,BSZ), dim3(256), 0, stream>>>(opim, weight, bias, out);
    // interpW - I = Kin @ Kinv - I  (into bufL, L consumed)
    mm_kernel<1,0,0,1><<<dim3(5,9,BSZ), dim3(256), 0, stream>>>(
        Kin, bufKinv, bufL, 576,576,576,576, 576,576,576,
        N2L,N2L,N2L, 0,0, nullptr, nullptr);
    // KiO = opiK @ Kinv           (into bufB)  [stable ordering: damp Kinv first]
    mm_kernel<2,0,0,0><<<dim3(5,18,BSZ), dim3(256), 0, stream>>>(
        opiK, bufKinv, bufB, 2304,576,576,576, 576,576,576,
        4*N2L,N2L,4*N2L, 0,0, nullptr, nullptr);
    // H' = KiO @ (interpW - I)    (into bufC)
    mm_kernel<2,0,0,0><<<dim3(5,18,BSZ), dim3(256), 0, stream>>>(
        bufB, bufL, bufC, 2304,576,576,576, 576,576,576,
        4*N2L,N2L,4*N2L, 0,0, nullptr, nullptr);
    // opiKW2 = W2 x opiK          (into bufB, KiO consumed)
    opiw2_k<<<dim3((BSZ*N2)/256), dim3(256), 0, stream>>>(opiK, W2, bufB);
    // full_AKA (output 2): prior + sum_{i,n} H'[i,m,n]*opiKW2[i,p,n] + jitter
    mm_kernel<1,0,1,2><<<dim3(5,9,BSZ), dim3(256), 0, stream>>>(
        bufC, bufB, out + 152064, 576,576,2304,576, 576,576,576,
        4*N2L,4*N2L,N2L, N2L,N2L, xin, W2);
}

// Round 4
// 1397.292 us; speedup vs baseline: 1.9164x; 1.2498x over previous
//
#include <hip/hip_runtime.h>
#include <math.h>

#define NPTS 576
#define N2 331776           // 576*576
#define BSZ 4
#define NB 64               // cholesky block
#define NT 9                // 576/64

#define INVL2 (1.0f/0.29311396f)

// ---------------------------------------------------------------------------
// copy xout = xin  (output 0)
// ---------------------------------------------------------------------------
__global__ void copy_xout(const float* __restrict__ xin, float* __restrict__ out) {
    int idx = blockIdx.x * 256 + threadIdx.x;   // 18*256 = 4608 exact
    out[idx] = xin[idx];
}

// ---------------------------------------------------------------------------
// build Kxx (+jitter) and opiK (4 planes) from xin
// ---------------------------------------------------------------------------
__global__ void build_k(const float* __restrict__ xin,
                        float* __restrict__ Kxx, float* __restrict__ opiK) {
    int idx = blockIdx.x * 256 + threadIdx.x;
    int b = idx / N2;
    int rem = idx - b * N2;
    int m = rem / NPTS;
    int nn = rem - m * NPTS;
    const float* xb = xin + (size_t)b * NPTS * 2;
    float xm0 = xb[m*2],  xm1 = xb[m*2+1];
    float xn0 = xb[nn*2], xn1 = xb[nn*2+1];
    float r0 = xm0 - xn0, r1 = xm1 - xn1;
    float u = (r0*r0 + r1*r1) * INVL2;
    float Kv = expf(-0.5f * u);
    Kxx[idx] = Kv + ((m == nn) ? 1e-5f : 0.0f);
    size_t base = (size_t)b * 4 * N2 + rem;
    opiK[base]          = Kv;
    opiK[base + N2]     = -r0 * INVL2 * Kv;
    opiK[base + 2*N2]   = -r1 * INVL2 * Kv;
    opiK[base + 3*N2]   = (u - 2.0f) * INVL2 * Kv;
}

// ---------------------------------------------------------------------------
// W2[i][j] = (1/64) sum_{o,c} w[o][c*4+i] * w[o][c*4+j]
// ---------------------------------------------------------------------------
__global__ void w2_k(const float* __restrict__ w, float* __restrict__ W2) {
    __shared__ float red[256];
    int tid = threadIdx.x;
    int pair = tid & 15;
    int slice = tid >> 4;
    int i = pair >> 2, j = pair & 3;
    float s = 0.0f;
    for (int o = slice * 4; o < slice * 4 + 4; ++o)
        for (int c = 0; c < 32; ++c)
            s += w[o*128 + c*4 + i] * w[o*128 + c*4 + j];
    red[tid] = s;
    __syncthreads();
    if (tid < 16) {
        float t = 0.0f;
        #pragma unroll
        for (int k = 0; k < 16; ++k) t += red[pair + 16*k];
        W2[pair] = t * (1.0f/64.0f);
    }
}

// ---------------------------------------------------------------------------
// blocked Cholesky: diag factor + Linv_kk (64x64) via 16x16 sub-block scheme
// ---------------------------------------------------------------------------
__global__ void chol_diag(float* __restrict__ A, float* __restrict__ LinvKK, int kb) {
    int b = blockIdx.x;
    float* Ab = A + (size_t)b * N2;
    __shared__ float T[NB][NB+1];
    __shared__ float V[NB][NB+1];
    __shared__ float tmp[16][17];
    int tid = threadIdx.x;   // 256
    int r0 = kb * NB;
    for (int idx = tid; idx < NB*NB; idx += 256) {
        int r = idx >> 6, c = idx & 63;
        T[r][c] = Ab[(size_t)(r0 + r) * NPTS + r0 + c];
        V[r][c] = 0.0f;
    }
    __syncthreads();
    // factor
    for (int j = 0; j < NB; ++j) {
        if (tid == 0) T[j][j] = sqrtf(fmaxf(T[j][j], 1e-12f));
        __syncthreads();
        float dj = T[j][j];
        for (int i = j + 1 + tid; i < NB; i += 256) T[i][j] /= dj;
        __syncthreads();
        int tr = NB - 1 - j;
        for (int idx = tid; idx < tr * tr; idx += 256) {
            int i = j + 1 + idx / tr;
            int c = j + 1 + idx % tr;
            T[i][c] -= T[i][j] * T[c][j];
        }
        __syncthreads();
    }
    // invert the four 16x16 diagonal sub-blocks (64 parallel column-solves)
    if (tid < 64) {
        int I = tid >> 4, c = tid & 15, base = I * 16;
        for (int i = c; i < 16; ++i) {
            float s = (i == c) ? 1.0f : 0.0f;
            for (int k = c; k < i; ++k) s -= T[base+i][base+k] * V[base+k][base+c];
            V[base+i][base+c] = s / T[base+i][base+i];
        }
    }
    __syncthreads();
    // off-diagonal sub-blocks by level: V[I][J] = -Vd[I] * (sum_K T[I][K] V[K][J])
    const int PI[6] = {1,2,3,2,3,3};
    const int PJ[6] = {0,1,2,0,1,0};
    int rr16 = tid >> 4, cc16 = tid & 15;
    for (int p = 0; p < 6; ++p) {
        int I = PI[p], J = PJ[p];
        float s = 0.0f;
        for (int K = J; K < I; ++K)
            #pragma unroll
            for (int t = 0; t < 16; ++t)
                s += T[I*16+rr16][K*16+t] * V[K*16+t][J*16+cc16];
        tmp[rr16][cc16] = s;
        __syncthreads();
        float s2 = 0.0f;
        for (int t = 0; t <= rr16; ++t) s2 += V[I*16+rr16][I*16+t] * tmp[t][cc16];
        __syncthreads();
        V[I*16+rr16][J*16+cc16] = -s2;
        __syncthreads();
    }
    // write back T (lower) and V
    float* Vg = LinvKK + ((size_t)b * NT + kb) * NB * NB;
    for (int idx = tid; idx < NB*NB; idx += 256) {
        int r = idx >> 6, c = idx & 63;
        if (c <= r) Ab[(size_t)(r0 + r) * NPTS + r0 + c] = T[r][c];
        Vg[idx] = V[r][c];
    }
}

// panel TRSM: L[ib,kb] = A[ib,kb] @ Linv_kk^T
__global__ void chol_trsm(float* __restrict__ A, const float* __restrict__ LinvKK, int kb) {
    int b = blockIdx.y;
    int ib = kb + 1 + blockIdx.x;
    float* Ab = A + (size_t)b * N2;
    const float* Vg = LinvKK + ((size_t)b * NT + kb) * NB * NB;
    __shared__ float At[NB][NB+1];
    __shared__ float Vs[NB][NB+1];
    int tid = threadIdx.x;
    int r0 = ib * NB, c0 = kb * NB;
    for (int idx = tid; idx < NB*NB; idx += 256) {
        int r = idx >> 6, c = idx & 63;
        At[r][c] = Ab[(size_t)(r0 + r) * NPTS + c0 + c];
        Vs[r][c] = Vg[idx];
    }
    __syncthreads();
    int tx = tid & 15, ty = tid >> 4;
    float acc[4][4] = {};
    for (int k = 0; k < NB; ++k) {
        float a[4], v[4];
        #pragma unroll
        for (int i = 0; i < 4; ++i) a[i] = At[ty*4+i][k];
        #pragma unroll
        for (int j = 0; j < 4; ++j) v[j] = Vs[tx*4+j][k];
        #pragma unroll
        for (int i = 0; i < 4; ++i)
            #pragma unroll
            for (int j = 0; j < 4; ++j) acc[i][j] += a[i] * v[j];
    }
    __syncthreads();
    #pragma unroll
    for (int i = 0; i < 4; ++i)
        #pragma unroll
        for (int j = 0; j < 4; ++j)
            Ab[(size_t)(r0 + ty*4+i) * NPTS + c0 + tx*4+j] = acc[i][j];
}

// trailing SYRK: A[ib,jb] -= L[ib,kb] @ L[jb,kb]^T
__global__ void chol_syrk(float* __restrict__ A, int kb) {
    int b = blockIdx.y;
    int p = blockIdx.x;
    int ib_rel = 0;
    while (p >= ib_rel + 1) { p -= ib_rel + 1; ib_rel++; }
    int ib = kb + 1 + ib_rel, jb = kb + 1 + p;
    float* Ab = A + (size_t)b * N2;
    __shared__ float Pi[NB][NB+1];
    __shared__ float Pj[NB][NB+1];
    int tid = threadIdx.x;
    int ri = ib * NB, rj = jb * NB, c0 = kb * NB;
    for (int idx = tid; idx < NB*NB; idx += 256) {
        int r = idx >> 6, c = idx & 63;
        Pi[r][c] = Ab[(size_t)(ri + r) * NPTS + c0 + c];
        Pj[r][c] = Ab[(size_t)(rj + r) * NPTS + c0 + c];
    }
    __syncthreads();
    int tx = tid & 15, ty = tid >> 4;
    float acc[4][4] = {};
    for (int k = 0; k < NB; ++k) {
        float a[4], v[4];
        #pragma unroll
        for (int i = 0; i < 4; ++i) a[i] = Pi[ty*4+i][k];
        #pragma unroll
        for (int j = 0; j < 4; ++j) v[j] = Pj[tx*4+j][k];
        #pragma unroll
        for (int i = 0; i < 4; ++i)
            #pragma unroll
            for (int j = 0; j < 4; ++j) acc[i][j] += a[i] * v[j];
    }
    #pragma unroll
    for (int i = 0; i < 4; ++i)
        #pragma unroll
        for (int j = 0; j < 4; ++j)
            Ab[(size_t)(ri + ty*4+i) * NPTS + rj + tx*4+j] -= acc[i][j];
}

// ---------------------------------------------------------------------------
// blocked triangular inverse. grid (4 splits of 16 cols, 9 block-cols, 4 batch)
// ---------------------------------------------------------------------------
__global__ __launch_bounds__(256)
void trinv_blk(const float* __restrict__ L, const float* __restrict__ LinvKK,
               float* __restrict__ Linv) {
    int sp = blockIdx.x, jb = blockIdx.y, b = blockIdx.z;
    const float* Lb = L + (size_t)b * N2;
    float* Xg = Linv + (size_t)b * N2;
    const float* Vg = LinvKK + (size_t)b * NT * NB * NB;
    int c0 = jb * NB + sp * 16;

    __shared__ float LsT[64][72];
    __shared__ float Xc[576][17];
    __shared__ float Ss[64][17];

    int tid = threadIdx.x;
    int tx = tid & 15, ty = tid >> 4;

    {
        const float* Vjj = Vg + (size_t)jb * NB * NB;
        int r = tid >> 2, c4 = (tid & 3) * 4;
        float4 v = *(const float4*)(Vjj + r * NB + sp * 16 + c4);
        Xc[r][c4+0] = v.x; Xc[r][c4+1] = v.y; Xc[r][c4+2] = v.z; Xc[r][c4+3] = v.w;
        *(float4*)(Xg + (size_t)(jb * NB + r) * NPTS + c0 + c4) = v;
    }
    __syncthreads();

    for (int ib = jb + 1; ib < NT; ++ib) {
        float acc[4] = {};
        for (int kb = jb; kb < ib; ++kb) {
            {
                int r = tid >> 2, t0 = (tid & 3) * 16;
                const float* src = Lb + (size_t)(ib * NB + r) * NPTS + kb * NB + t0;
                #pragma unroll
                for (int q = 0; q < 4; ++q) {
                    float4 v = *(const float4*)(src + q * 4);
                    LsT[t0 + q*4 + 0][r] = v.x;
                    LsT[t0 + q*4 + 1][r] = v.y;
                    LsT[t0 + q*4 + 2][r] = v.z;
                    LsT[t0 + q*4 + 3][r] = v.w;
                }
            }
            __syncthreads();
            int xbase = (kb - jb) * 64;
            #pragma unroll 8
            for (int t = 0; t < 64; ++t) {
                float a4[4]; *(float4*)a4 = *(const float4*)&LsT[t][ty*4];
                float xv = Xc[xbase + t][tx];
                #pragma unroll
                for (int i = 0; i < 4; ++i) acc[i] += a4[i] * xv;
            }
            __syncthreads();
        }
        #pragma unroll
        for (int i = 0; i < 4; ++i) Ss[ty*4+i][tx] = acc[i];
        {
            const float* Vii = Vg + (size_t)ib * NB * NB;
            int r = tid >> 2, t0 = (tid & 3) * 16;
            #pragma unroll
            for (int q = 0; q < 4; ++q) {
                float4 v = *(const float4*)(Vii + r * NB + t0 + q * 4);
                LsT[t0 + q*4 + 0][r] = v.x;
                LsT[t0 + q*4 + 1][r] = v.y;
                LsT[t0 + q*4 + 2][r] = v.z;
                LsT[t0 + q*4 + 3][r] = v.w;
            }
        }
        __syncthreads();
        float acc2[4] = {};
        #pragma unroll 8
        for (int t = 0; t < 64; ++t) {
            float a4[4]; *(float4*)a4 = *(const float4*)&LsT[t][ty*4];
            float sv = Ss[t][tx];
            #pragma unroll
            for (int i = 0; i < 4; ++i) acc2[i] += a4[i] * sv;
        }
        int obase = (ib - jb) * 64;
        #pragma unroll
        for (int i = 0; i < 4; ++i) {
            float v = -acc2[i];
            Xc[obase + ty*4 + i][tx] = v;
            Xg[(size_t)(ib * NB + ty*4 + i) * NPTS + c0 + tx] = v;
        }
        __syncthreads();
    }
}

// ---------------------------------------------------------------------------
// batched tiled matmul, 64x128 C-tile, 256 threads, register-prefetched.
// TA=1: C = A^T B.  TB=1: C = A B^T.
// SK: K-split factor (blockIdx.z = b*SK + sp; partial sp at C + sp*sSplit).
// TRI=1: skip k < max(m0,n0) (for Linv^T Linv).
// ---------------------------------------------------------------------------
template<int TA, int TB, int SK, int TRI>
__global__ __launch_bounds__(256)
void mm_kernel(const float* __restrict__ Aall, const float* __restrict__ Ball,
               float* __restrict__ Call,
               int M, int N, int K, int planeK,
               int lda, int ldb, int ldc,
               long sA, long sB, long sC, long pA, long pB, long sSplit)
{
    int z = blockIdx.z;
    int sp = (SK > 1) ? (z % SK) : 0;
    int b  = (SK > 1) ? (z / SK) : z;
    const float* A = Aall + (size_t)b * sA;
    const float* B = Ball + (size_t)b * sB;
    float* C = Call + (size_t)b * sC + (size_t)sp * sSplit;
    int n0 = blockIdx.x * 128;
    int m0 = blockIdx.y * 64;

    __shared__ float As[16][68];
    __shared__ float Bs[16][132];

    int tid = threadIdx.x;
    int tx = tid & 15, ty = tid >> 4;

    float acc[2][4][4] = {};
    bool mFull = (m0 + 64 <= M);
    bool nFull = (n0 + 128 <= N);

    int triBeg = 0;
    if (TRI) { int mx = (m0 > n0 ? m0 : n0); triBeg = mx & ~15; }
    int kBeg = triBeg, kEnd = K;
    if (SK == 2) {
        int len = K - triBeg;
        int half = ((len >> 1) + 15) & ~15;
        kBeg = triBeg + sp * half;
        kEnd = sp ? K : (triBeg + half);
    }

    float avr[4];        // A fragment registers (one float4 worth)
    float bvr[2][4];     // B fragment registers

    auto loadA = [&](int k0) {
        int plane = k0 / planeK;
        int koff  = k0 - plane * planeK;
        if (TA == 0) {
            const float* Ab = A + (size_t)pA * plane;
            int r = tid >> 2, c4 = (tid & 3) * 4;
            int gm = m0 + r;
            if (mFull || gm < M) {
                float4 t = *(const float4*)(Ab + (size_t)gm * lda + koff + c4);
                avr[0]=t.x; avr[1]=t.y; avr[2]=t.z; avr[3]=t.w;
            } else { avr[0]=avr[1]=avr[2]=avr[3]=0.0f; }
        } else {
            int r = tid >> 4, c4 = (tid & 15) * 4;
            const float* p = A + (size_t)(koff + r) * lda + m0 + c4;
            if (mFull) {
                float4 t = *(const float4*)p;
                avr[0]=t.x; avr[1]=t.y; avr[2]=t.z; avr[3]=t.w;
            } else {
                #pragma unroll
                for (int jj = 0; jj < 4; ++jj)
                    avr[jj] = (m0 + c4 + jj < M) ? p[jj] : 0.0f;
            }
        }
    };
    auto storeA = [&]() {
        if (TA == 0) {
            int r = tid >> 2, c4 = (tid & 3) * 4;
            #pragma unroll
            for (int q = 0; q < 4; ++q) As[c4+q][r] = avr[q];
        } else {
            int r = tid >> 4, c4 = (tid & 15) * 4;
            #pragma unroll
            for (int q = 0; q < 4; ++q) As[r][c4+q] = avr[q];
        }
    };
    auto loadB = [&](int k0) {
        int plane = k0 / planeK;
        int koff  = k0 - plane * planeK;
        if (TB == 0) {
            int r = tid >> 4, c8 = (tid & 15) * 8;
            const float* p = B + (size_t)(koff + r) * ldb + n0 + c8;
            if (nFull) {
                float4 t0 = *(const float4*)p;
                float4 t1 = *(const float4*)(p + 4);
                bvr[0][0]=t0.x; bvr[0][1]=t0.y; bvr[0][2]=t0.z; bvr[0][3]=t0.w;
                bvr[1][0]=t1.x; bvr[1][1]=t1.y; bvr[1][2]=t1.z; bvr[1][3]=t1.w;
            } else {
                #pragma unroll
                for (int jj = 0; jj < 4; ++jj)
                    bvr[0][jj] = (n0 + c8 + jj < N) ? p[jj] : 0.0f;
                #pragma unroll
                for (int jj = 0; jj < 4; ++jj)
                    bvr[1][jj] = (n0 + c8 + 4 + jj < N) ? p[4+jj] : 0.0f;
            }
        } else {
            const float* Bb = B + (size_t)pB * plane;
            int r = tid >> 2, c4 = (tid & 3) * 4;
            #pragma unroll
            for (int pass = 0; pass < 2; ++pass) {
                int gp = n0 + r + pass * 64;
                if (nFull || gp < N) {
                    float4 t = *(const float4*)(Bb + (size_t)gp * ldb + koff + c4);
                    bvr[pass][0]=t.x; bvr[pass][1]=t.y; bvr[pass][2]=t.z; bvr[pass][3]=t.w;
                } else {
                    bvr[pass][0]=bvr[pass][1]=bvr[pass][2]=bvr[pass][3]=0.0f;
                }
            }
        }
    };
    auto storeB = [&]() {
        if (TB == 0) {
            int r = tid >> 4, c8 = (tid & 15) * 8;
            #pragma unroll
            for (int q = 0; q < 4; ++q) Bs[r][c8+q]   = bvr[0][q];
            #pragma unroll
            for (int q = 0; q < 4; ++q) Bs[r][c8+4+q] = bvr[1][q];
        } else {
            int r = tid >> 2, c4 = (tid & 3) * 4;
            #pragma unroll
            for (int pass = 0; pass < 2; ++pass)
                #pragma unroll
                for (int q = 0; q < 4; ++q) Bs[c4+q][r + pass*64] = bvr[pass][q];
        }
    };

    loadA(kBeg); loadB(kBeg);
    for (int k0 = kBeg; k0 < kEnd; k0 += 16) {
        storeA(); storeB();
        __syncthreads();
        if (k0 + 16 < kEnd) { loadA(k0 + 16); loadB(k0 + 16); }
        #pragma unroll
        for (int kk = 0; kk < 16; ++kk) {
            float a[4], bb[2][4];
            *(float4*)a     = *(const float4*)&As[kk][ty*4];
            *(float4*)bb[0] = *(const float4*)&Bs[kk][tx*4];
            *(float4*)bb[1] = *(const float4*)&Bs[kk][64 + tx*4];
            #pragma unroll
            for (int jh = 0; jh < 2; ++jh)
                #pragma unroll
                for (int i = 0; i < 4; ++i)
                    #pragma unroll
                    for (int j = 0; j < 4; ++j)
                        acc[jh][i][j] += a[i] * bb[jh][j];
        }
        __syncthreads();
    }

    #pragma unroll
    for (int i = 0; i < 4; ++i) {
        int gm = m0 + ty*4 + i;
        if (gm >= M) continue;
        #pragma unroll
        for (int jh = 0; jh < 2; ++jh)
            #pragma unroll
            for (int j = 0; j < 4; ++j) {
                int gn = n0 + jh*64 + tx*4 + j;
                if (gn >= N) continue;
                C[(size_t)gm * ldc + gn] = acc[jh][i][j];
            }
    }
}

// ---------------------------------------------------------------------------
// combine kernels for split-K partials
// ---------------------------------------------------------------------------
__global__ void combine_add4(const float* __restrict__ a, const float* __restrict__ b,
                             float* __restrict__ o) {
    int i = blockIdx.x * 256 + threadIdx.x;
    float4 x = ((const float4*)a)[i];
    float4 y = ((const float4*)b)[i];
    float4 r; r.x=x.x+y.x; r.y=x.y+y.y; r.z=x.z+y.z; r.w=x.w+y.w;
    ((float4*)o)[i] = r;
}

__global__ void combine_subI(const float* __restrict__ a, const float* __restrict__ b2,
                             float* __restrict__ o) {
    int idx = blockIdx.x * 256 + threadIdx.x;   // over 4*N2
    int rem = idx % N2;
    int m = rem / NPTS, n = rem - m * NPTS;
    o[idx] = a[idx] + b2[idx] - ((m == n) ? 1.0f : 0.0f);
}

__global__ void combine_prior(const float* __restrict__ a, const float* __restrict__ b2,
                              const float* __restrict__ xin, const float* __restrict__ W2g,
                              float* __restrict__ o) {
    __shared__ float w[16];
    int tid = threadIdx.x;
    if (tid < 16) w[tid] = W2g[tid];
    __syncthreads();
    int idx = blockIdx.x * 256 + tid;           // over 4*N2
    int b = idx / N2;
    int rem = idx - b * N2;
    int m = rem / NPTS, n = rem - m * NPTS;
    const float* xb = xin + (size_t)b * NPTS * 2;
    float r0 = xb[m*2+0] - xb[n*2+0];
    float r1 = xb[m*2+1] - xb[n*2+1];
    float u = (r0*r0 + r1*r1) * INVL2;
    float Kv = expf(-0.5f * u);
    float i2 = INVL2 * INVL2;
    float gK0 = r0 * INVL2 * Kv;
    float gK1 = r1 * INVL2 * Kv;
    float lapK = (u - 2.0f) * INVL2 * Kv;
    float gg00 = (INVL2 - r0*r0*i2) * Kv;
    float gg01 = (-r0*r1*i2) * Kv;
    float gg11 = (INVL2 - r1*r1*i2) * Kv;
    float gl0 = r0 * i2 * (4.0f - u) * Kv;
    float gl1 = r1 * i2 * (4.0f - u) * Kv;
    float ll = ((u-2.0f)*(u-2.0f) - 4.0f*u + 4.0f) * i2 * Kv;
    float prior =
          w[0]*Kv + w[1]*gK0 + w[2]*gK1 + w[3]*lapK
        + w[4]*(-gK0) + w[5]*gg00 + w[6]*gg01 + w[7]*gl0
        + w[8]*(-gK1) + w[9]*gg01 + w[10]*gg11 + w[11]*gl1
        + w[12]*lapK + w[13]*(-gl0) + w[14]*(-gl1) + w[15]*ll;
    float v = a[idx] + b2[idx] + prior;
    if (m == n) v += 1.1e-4f;
    o[idx] = v;
}

// ---------------------------------------------------------------------------
// opiKW2[b][i] = sum_j W2[i][j] * opiK[b][j]
// ---------------------------------------------------------------------------
__global__ void opiw2_k(const float* __restrict__ opiK, const float* __restrict__ W2,
                        float* __restrict__ outB) {
    int idx = blockIdx.x * 256 + threadIdx.x;
    int b = idx / N2;
    int rem = idx - b * N2;
    size_t base = (size_t)b * 4 * N2 + rem;
    float k0 = opiK[base], k1 = opiK[base + N2], k2 = opiK[base + 2*N2], k3 = opiK[base + 3*N2];
    #pragma unroll
    for (int i = 0; i < 4; ++i)
        outB[base + (size_t)i * N2] = W2[i*4+0]*k0 + W2[i*4+1]*k1 + W2[i*4+2]*k2 + W2[i*4+3]*k3;
}

// ---------------------------------------------------------------------------
// Amean[b,m,o] = sum_{c,k} opimean[b,k,m,c] * weight[o, c*4+k] + bias[o]
// ---------------------------------------------------------------------------
__global__ __launch_bounds__(256)
void amean_k(const float* __restrict__ opimean, const float* __restrict__ weight,
             const float* __restrict__ bias, float* __restrict__ out) {
    int b = blockIdx.y;
    int m0 = blockIdx.x * 32;
    __shared__ float Wl[64][128];
    __shared__ float om[32][128];
    int tid = threadIdx.x;
    for (int idx = tid; idx < 64*128; idx += 256) Wl[idx / 128][idx & 127] = weight[idx];
    for (int idx = tid; idx < 32*128; idx += 256) {
        int m = idx >> 7, ck = idx & 127, c = ck >> 2, kop = ck & 3;
        om[m][ck] = opimean[((size_t)b * 4 + kop) * NPTS * 32 + (size_t)(m0 + m) * 32 + c];
    }
    __syncthreads();
    int ml = tid >> 3, o0 = (tid & 7) * 8;
    float acc[8] = {};
    for (int ck = 0; ck < 128; ++ck) {
        float v = om[ml][ck];
        #pragma unroll
        for (int q = 0; q < 8; ++q) acc[q] += v * Wl[o0+q][ck];
    }
    #pragma unroll
    for (int q = 0; q < 8; ++q)
        out[4608 + ((size_t)b * NPTS + m0 + ml) * 64 + o0 + q] = acc[q] + bias[o0+q];
}

// ---------------------------------------------------------------------------
extern "C" void kernel_launch(void* const* d_in, const int* in_sizes, int n_in,
                              void* d_out, int out_size, void* d_ws, size_t ws_size,
                              hipStream_t stream) {
    const float* xin    = (const float*)d_in[0];
    const float* meanin = (const float*)d_in[1];
    const float* Kin    = (const float*)d_in[2];
    const float* weight = (const float*)d_in[3];
    const float* bias   = (const float*)d_in[4];
    float* out = (float*)d_out;
    float* ws  = (float*)d_ws;

    const long N2L = N2;
    float* W2      = ws;                       // 16 (pad 64)
    float* LinvKK  = ws + 64;                  // 4*9*4096 = 147456
    float* bufL    = LinvKK + 147456;          // 4*N2  (Kxx/L, later interpW - I)
    float* bufLinv = bufL + 4*N2L;             // 4*N2  (Linv, later solm/opim)
    float* bufKinv = bufLinv + 4*N2L;          // 4*N2  (Kinv, later final partial 0)
    float* opiK    = bufKinv + 4*N2L;          // 16*N2 (opiK, later final partial 1)
    float* bufB    = opiK + 16*N2L;            // 16*N2 (Kinv partials, KiO, opiKW2)
    float* bufC    = bufB + 16*N2L;            // 16*N2 (interpW partials, H')
    float* solm    = bufLinv;                  // reuse after Kinv done
    float* opim    = bufLinv + 73728;

    // zero Linv (upper triangle must be 0)
    hipMemsetAsync(bufLinv, 0, (size_t)4 * N2 * sizeof(float), stream);
    // output 0: xout = xin
    copy_xout<<<dim3(18), dim3(256), 0, stream>>>(xin, out);
    // Kxx (+jitter) and opiK
    build_k<<<dim3((BSZ*N2)/256), dim3(256), 0, stream>>>(xin, bufL, opiK);
    // W2
    w2_k<<<dim3(1), dim3(256), 0, stream>>>(weight, W2);
    // blocked Cholesky of Kxx -> L (lower) in bufL
    for (int kb = 0; kb < NT; ++kb) {
        chol_diag<<<dim3(BSZ), dim3(256), 0, stream>>>(bufL, LinvKK, kb);
        int t = NT - 1 - kb;
        if (t > 0) {
            chol_trsm<<<dim3(t, BSZ), dim3(256), 0, stream>>>(bufL, LinvKK, kb);
            chol_syrk<<<dim3(t*(t+1)/2, BSZ), dim3(256), 0, stream>>>(bufL, kb);
        }
    }
    // blocked triangular inverse -> Linv
    trinv_blk<<<dim3(4, NT, BSZ), dim3(256), 0, stream>>>(bufL, LinvKK, bufLinv);
    // Kinv = Linv^T @ Linv  (split-K=2, tri-start; partials -> bufB)
    mm_kernel<1,0,2,1><<<dim3(5,9,BSZ*2), dim3(256), 0, stream>>>(
        bufLinv, bufLinv, bufB, 576,576,576,576, 576,576,576,
        N2L,N2L,N2L, 0,0, 4*N2L);
    combine_add4<<<dim3(1296), dim3(256), 0, stream>>>(bufB, bufB + 4*N2L, bufKinv);
    // sol_mean = Kinv @ meanin
    mm_kernel<0,0,1,0><<<dim3(1,9,BSZ), dim3(256), 0, stream>>>(
        bufKinv, meanin, solm, 576,32,576,576, 576,32,32,
        N2L,18432,18432, 0,0, 0);
    // opimean = opiK @ sol_mean
    mm_kernel<0,0,1,0><<<dim3(1,36,BSZ), dim3(256), 0, stream>>>(
        opiK, solm, opim, 2304,32,576,576, 576,32,32,
        4*N2L,18432,73728, 0,0, 0);
    // Amean (output 1)
    amean_k<<<dim3(18,BSZ), dim3(256), 0, stream>>>(opim, weight, bias, out);
    // interpW - I = Kin @ Kinv - I  (split-K=2; partials -> bufC; combine -> bufL)
    mm_kernel<0,0,2,0><<<dim3(5,9,BSZ*2), dim3(256), 0, stream>>>(
        Kin, bufKinv, bufC, 576,576,576,576, 576,576,576,
        N2L,N2L,N2L, 0,0, 4*N2L);
    combine_subI<<<dim3(5184), dim3(256), 0, stream>>>(bufC, bufC + 4*N2L, bufL);
    // KiO = opiK @ Kinv            (into bufB)
    mm_kernel<0,0,1,0><<<dim3(5,36,BSZ), dim3(256), 0, stream>>>(
        opiK, bufKinv, bufB, 2304,576,576,576, 576,576,576,
        4*N2L,N2L,4*N2L, 0,0, 0);
    // H' = KiO @ (interpW - I)     (into bufC)
    mm_kernel<0,0,1,0><<<dim3(5,36,BSZ), dim3(256), 0, stream>>>(
        bufB, bufL, bufC, 2304,576,576,576, 576,576,576,
        4*N2L,N2L,4*N2L, 0,0, 0);
    // opiKW2 = W2 x opiK           (into bufB, KiO consumed)
    opiw2_k<<<dim3((BSZ*N2)/256), dim3(256), 0, stream>>>(opiK, W2, bufB);
    // final AKA partial GEMM (split-K=2): partials -> bufKinv, opiK (both dead)
    mm_kernel<0,1,2,0><<<dim3(5,9,BSZ*2), dim3(256), 0, stream>>>(
        bufC, bufB, bufKinv, 576,576,2304,576, 576,576,576,
        4*N2L,4*N2L,N2L, N2L,N2L, 4*N2L);
    // output 2: combine partials + analytic prior + jitter
    combine_prior<<<dim3(5184), dim3(256), 0, stream>>>(
        bufKinv, bufKinv + 4*N2L, xin, W2, out + 152064);
}